// Round 3
// baseline (59.985 us; speedup 1.0000x reference)
//
#include <hip/hip_runtime.h>
#include <math.h>

namespace {

constexpr int kD = 1024;
constexpr int kL = 1024;
constexpr int kN = 16;

// block = one (b,d): 1024 threads, each owns 4 l-steps x 4 n-states.
// lane = 4*chunk_in_wave + ng ; wave covers 64 consecutive l.
__global__ __launch_bounds__(1024, 8)
void selscan(const float* __restrict__ u,
             const float* __restrict__ delta,
             const float* __restrict__ A,
             const float* __restrict__ Bm,
             const float* __restrict__ Cm,
             const float* __restrict__ Dv,
             const float* __restrict__ z,
             float* __restrict__ out)
{
    __shared__ __align__(16) float swa[16][16];  // [wave][n] chunk-product a
    __shared__ __align__(16) float swx[16][16];  // [wave][n] chunk-scan x
    __shared__ __align__(16) float sci[16][16];  // [wave][n] carry into wave

    const int bd   = blockIdx.x;
    const int b    = bd >> 10;            // kD = 1024
    const int d    = bd & (kD - 1);
    const int t    = threadIdx.x;
    const int wave = t >> 6;
    const int lane = t & 63;
    const int ng   = lane & 3;            // n-group: states 4*ng .. 4*ng+3
    const int n0   = ng << 2;
    const int l0   = (t >> 2) << 2;       // this thread's chunk base in l
    const size_t base = (size_t)bd * kL;

    // ---- dt = softplus(delta), dtu = dt*u for the 4-step chunk ----
    float dt[4], dtu[4];
    {
        float4 dv = *(const float4*)(delta + base + l0);
        float4 uv = *(const float4*)(u + base + l0);
        float dd[4] = {dv.x, dv.y, dv.z, dv.w};
        float uu[4] = {uv.x, uv.y, uv.z, uv.w};
        #pragma unroll
        for (int s = 0; s < 4; ++s) {
            float x  = dd[s];
            float sp = fmaxf(x, 0.f) + __logf(1.f + __expf(-fabsf(x)));
            dt[s]  = sp;
            dtu[s] = sp * uu[s];
        }
    }

    // ---- A row (pre-scaled by log2e for exp2) ----
    const float LOG2E = 1.4426950408889634f;
    float cj[4];
    {
        float4 a4 = *(const float4*)(A + d * kN + n0);
        cj[0] = a4.x * LOG2E; cj[1] = a4.y * LOG2E;
        cj[2] = a4.z * LOG2E; cj[3] = a4.w * LOG2E;
    }

    // ---- Phase 1: local scan; accumulate y_local and Q = P*C ----
    float Q[4][4];
    float y[4] = {0.f, 0.f, 0.f, 0.f};
    float a_s[4], x_s[4];
    const int rowbase = (b << 4) + n0;
    #pragma unroll
    for (int j = 0; j < 4; ++j) {
        const float* Bp = Bm + (size_t)(rowbase + j) * kL + l0;
        const float* Cp = Cm + (size_t)(rowbase + j) * kL + l0;
        float4 b4 = *(const float4*)Bp;
        float4 c4 = *(const float4*)Cp;
        float Bv[4] = {b4.x, b4.y, b4.z, b4.w};
        float Cv[4] = {c4.x, c4.y, c4.z, c4.w};
        float x = 0.f, p = 1.f;
        #pragma unroll
        for (int s = 0; s < 4; ++s) {
            float e = __builtin_amdgcn_exp2f(dt[s] * cj[j]);
            x = fmaf(e, x, dtu[s] * Bv[s]);
            p *= e;
            Q[j][s] = p * Cv[s];
            y[s] = fmaf(x, Cv[s], y[s]);
        }
        a_s[j] = p;
        x_s[j] = x;
    }

    // ---- In-wave Hillis-Steele inclusive scan over 16 chunks (stride 4) ----
    #pragma unroll
    for (int dlt = 4; dlt <= 32; dlt <<= 1) {
        #pragma unroll
        for (int j = 0; j < 4; ++j) {
            float ain = __shfl_up(a_s[j], dlt, 64);
            float xin = __shfl_up(x_s[j], dlt, 64);
            bool act = (lane >= dlt);
            ain = act ? ain : 1.f;
            xin = act ? xin : 0.f;
            x_s[j] = fmaf(a_s[j], xin, x_s[j]);
            a_s[j] *= ain;
        }
    }

    // ---- Wave summaries (chunk 15 lanes hold wave-inclusive totals) ----
    if (lane >= 60) {
        *(float4*)&swa[wave][n0] = make_float4(a_s[0], a_s[1], a_s[2], a_s[3]);
        *(float4*)&swx[wave][n0] = make_float4(x_s[0], x_s[1], x_s[2], x_s[3]);
    }
    __syncthreads();

    // ---- Log-time scan of the 16 wave summaries (single wave) ----
    if (wave == 0) {
        int w = lane >> 2, q = lane & 3;           // lane covers (wave w, 4 n)
        float4 aa = *(const float4*)&swa[w][q << 2];
        float4 xx = *(const float4*)&swx[w][q << 2];
        float as[4] = {aa.x, aa.y, aa.z, aa.w};
        float xs[4] = {xx.x, xx.y, xx.z, xx.w};
        #pragma unroll
        for (int dlt = 4; dlt <= 32; dlt <<= 1) {
            #pragma unroll
            for (int j = 0; j < 4; ++j) {
                float ain = __shfl_up(as[j], dlt, 64);
                float xin = __shfl_up(xs[j], dlt, 64);
                bool act = (lane >= dlt);
                ain = act ? ain : 1.f;
                xin = act ? xin : 0.f;
                xs[j] = fmaf(as[j], xin, xs[j]);
                as[j] *= ain;
            }
        }
        // exclusive (carry INTO wave w) = inclusive through w-1
        float ex[4];
        #pragma unroll
        for (int j = 0; j < 4; ++j) {
            float xv = __shfl_up(xs[j], 4, 64);
            ex[j] = (lane >= 4) ? xv : 0.f;
        }
        *(float4*)&sci[w][q << 2] = make_float4(ex[0], ex[1], ex[2], ex[3]);
    }
    __syncthreads();

    // ---- Carry into this thread's chunk ----
    float4 wc4 = *(const float4*)&sci[wave][n0];
    float wc[4] = {wc4.x, wc4.y, wc4.z, wc4.w};
    float carry[4];
    #pragma unroll
    for (int j = 0; j < 4; ++j) {
        float av = __shfl_up(a_s[j], 4, 64);
        float xv = __shfl_up(x_s[j], 4, 64);
        float ea = (lane >= 4) ? av : 1.f;
        float ex = (lane >= 4) ? xv : 0.f;
        carry[j] = fmaf(ea, wc[j], ex);
    }

    // ---- Phase 2: y += carry_j * Q_j ----
    #pragma unroll
    for (int j = 0; j < 4; ++j)
        #pragma unroll
        for (int s = 0; s < 4; ++s)
            y[s] = fmaf(carry[j], Q[j][s], y[s]);

    // ---- Reduce over the 4 n-groups (lane bits 0-1) ----
    #pragma unroll
    for (int s = 0; s < 4; ++s) {
        y[s] += __shfl_xor(y[s], 1, 64);
        y[s] += __shfl_xor(y[s], 2, 64);
    }
    float yo = (ng == 0) ? y[0] : (ng == 1) ? y[1] : (ng == 2) ? y[2] : y[3];

    // ---- Epilogue: out[base+t] = (y + u*D) * silu(z)  (fully coalesced) ----
    const float D_d = Dv[d];
    float uo = u[base + t];
    float zo = z[base + t];
    float sig = __builtin_amdgcn_rcpf(1.f + __expf(-zo));
    out[base + t] = (yo + uo * D_d) * zo * sig;
}

}  // namespace

extern "C" void kernel_launch(void* const* d_in, const int* in_sizes, int n_in,
                              void* d_out, int out_size, void* d_ws, size_t ws_size,
                              hipStream_t stream) {
    const float* u     = (const float*)d_in[0];
    const float* delta = (const float*)d_in[1];
    const float* A     = (const float*)d_in[2];
    const float* Bm    = (const float*)d_in[3];
    const float* Cm    = (const float*)d_in[4];
    const float* Dv    = (const float*)d_in[5];
    const float* z     = (const float*)d_in[6];
    float* out = (float*)d_out;

    dim3 grid(2 * kD);
    dim3 block(1024);
    hipLaunchKernelGGL(selscan, grid, block, 0, stream,
                       u, delta, A, Bm, Cm, Dv, z, out);
}